// Round 1
// baseline (360.253 us; speedup 1.0000x reference)
//
#include <hip/hip_runtime.h>

// Depthwise 7x7 cross-correlation, same padding.
// x:    [8, 256, 64, 64]   fp32
// tmpl: [8, 8, 256, 7, 7]  fp32  (nt, bs, nc, ht, wt)
// out:  [8, 8, 256, 64, 64] fp32
//
// One block per (b,c) plane; loops over all 8 templates so x is staged into
// LDS once and reused 8x. Each thread computes a 4x4 output tile.
// LDS plane is zero-padded: rows 0..69 (y = row-3), cols 0..71 (x = col-4;
// left pad 4 keeps ds_read_b128 16B-aligned).

#define NT 8
#define BS 8
#define NC 256
#define HW 64
#define PLANE (HW * HW)          // 4096
#define LROWS 70
#define LSTR  72                 // row stride in floats; 72*4 B = 288 B (16B mult)
#define TPL_STR 52               // padded template stride (4-aligned for float4)

__global__ __launch_bounds__(256) void dwxcorr_kernel(
    const float* __restrict__ x,
    const float* __restrict__ tm,
    float* __restrict__ out)
{
    __shared__ __align__(16) float xpl[LROWS * LSTR];     // 20160 B
    __shared__ __align__(16) float tpl[NT * TPL_STR];     // 1664 B

    const int bc  = blockIdx.x;          // b*256 + c, 0..2047
    const int tid = threadIdx.x;

    // ---- zero the whole padded plane (pads must be 0) ----
    for (int i = tid; i < LROWS * LSTR; i += 256) xpl[i] = 0.0f;
    __syncthreads();

    // ---- stage x interior: 1024 float4 loads, coalesced ----
    const float* xp = x + bc * PLANE;
    for (int i = tid; i < PLANE / 4; i += 256) {
        float4 v = ((const float4*)xp)[i];
        int row = i >> 4;              // 16 float4 per 64-wide row
        int c4  = (i & 15) << 2;
        *(float4*)&xpl[(row + 3) * LSTR + 4 + c4] = v;
    }

    // ---- stage all 8 templates for this (b,c) ----
    // flat idx = t*(8*256*49) + (b*256+c)*49 + k
    const float* tb = tm + bc * 49;
    for (int i = tid; i < NT * 49; i += 256) {
        int t = i / 49;
        int k = i - t * 49;
        tpl[t * TPL_STR + k] = tb[t * (NT * NC * 49) + k];
    }
    __syncthreads();

    // ---- compute: thread (tx,ty) -> output tile rows 4*ty.., cols 4*tx.. ----
    const int tx = tid & 15, ty = tid >> 4;
    const int col0 = tx << 2, row0 = ty << 2;

    for (int t = 0; t < NT; ++t) {
        // broadcast template taps into registers (13 x ds_read_b128, same addr)
        float w[TPL_STR];
        const float4* wp = (const float4*)&tpl[t * TPL_STR];
        #pragma unroll
        for (int q = 0; q < TPL_STR / 4; ++q) {
            float4 v = wp[q];
            w[4 * q + 0] = v.x; w[4 * q + 1] = v.y;
            w[4 * q + 2] = v.z; w[4 * q + 3] = v.w;
        }

        float acc[4][4];
        #pragma unroll
        for (int r = 0; r < 4; ++r)
            #pragma unroll
            for (int j = 0; j < 4; ++j) acc[r][j] = 0.0f;

        // input rows needed for output rows row0..row0+3: LDS rows row0..row0+9
        #pragma unroll
        for (int ir = 0; ir < 10; ++ir) {
            const float* rowp = &xpl[(row0 + ir) * LSTR + col0];
            float xw[12];
            float4 a = *(const float4*)(rowp);
            float4 b = *(const float4*)(rowp + 4);
            float4 c = *(const float4*)(rowp + 8);
            xw[0] = a.x; xw[1]  = a.y; xw[2]  = a.z; xw[3]  = a.w;
            xw[4] = b.x; xw[5]  = b.y; xw[6]  = b.z; xw[7]  = b.w;
            xw[8] = c.x; xw[9]  = c.y; xw[10] = c.z; xw[11] = c.w;

            #pragma unroll
            for (int r = 0; r < 4; ++r) {
                const int ky = ir - r;            // compile-time after unroll
                if (ky >= 0 && ky < 7) {
                    #pragma unroll
                    for (int kx = 0; kx < 7; ++kx) {
                        const float tv = w[ky * 7 + kx];
                        #pragma unroll
                        for (int j = 0; j < 4; ++j)
                            acc[r][j] = fmaf(xw[j + kx + 1], tv, acc[r][j]);
                    }
                }
            }
        }

        // ---- store 4 rows x float4, coalesced across tx ----
        float* op = out + (size_t)(t * (BS * NC) + bc) * PLANE + row0 * HW + col0;
        #pragma unroll
        for (int r = 0; r < 4; ++r) {
            float4 v = make_float4(acc[r][0], acc[r][1], acc[r][2], acc[r][3]);
            *(float4*)(op + r * HW) = v;
        }
    }
}

extern "C" void kernel_launch(void* const* d_in, const int* in_sizes, int n_in,
                              void* d_out, int out_size, void* d_ws, size_t ws_size,
                              hipStream_t stream) {
    const float* x  = (const float*)d_in[0];
    const float* tm = (const float*)d_in[1];
    float* out = (float*)d_out;
    dwxcorr_kernel<<<BS * NC, 256, 0, stream>>>(x, tm, out);
}